// Round 9
// baseline (1227.259 us; speedup 1.0000x reference)
//
#include <hip/hip_runtime.h>
#include <stdint.h>

// ---------------------------------------------------------------------------
// GCN 5-layer, N=50000, E=600000.  out = ((Anorm @ h) @ W) + b per layer.
// Activations: f16 hi/lo (22-bit mantissa). Packed (h,l) u32 per feature for
// the agg gather; hi/lo planes for GEMM staging.
// Aggregation: FEATURE-SLICED, XCD-PINNED. Slice = 64B (one cache line),
// blockIdx = rowchunk*NSLICE + slice so slice s lands on XCD s%8 -> per-XCD
// gather working set 51MB -> 6.4MB (L2/L3-resident instead of HBM-random).
// Per (row,slice): 8 groups x 8 lanes, 8 edges in flight, shfl_xor reduce.
// GEMM = f16x3 split MFMA, 32x32x16 fragments, BM=64 x BN=256 (R8 version).
// R6: no agg+GEMM fusion. R7: BM=64 > BM=128. R8: GEMM not the binder.
// ---------------------------------------------------------------------------

typedef _Float16 v8h __attribute__((ext_vector_type(8)));
typedef _Float16 v4h __attribute__((ext_vector_type(4)));
typedef _Float16 v2h __attribute__((ext_vector_type(2)));
typedef float v4f __attribute__((ext_vector_type(4)));
typedef float v16f __attribute__((ext_vector_type(16)));

// ---------------- CSR build ----------------
__global__ void count_edges(const int* __restrict__ dst, int E, int* __restrict__ counts) {
    int i = blockIdx.x * blockDim.x + threadIdx.x;
    if (i < E) atomicAdd(&counts[dst[i]], 1);
}

__global__ void block_sums(const int* __restrict__ counts, int n, int* __restrict__ partial) {
    __shared__ int red[256];
    int t = threadIdx.x;
    int i = blockIdx.x * 256 + t;
    red[t] = (i < n) ? counts[i] : 0;
    __syncthreads();
    #pragma unroll
    for (int off = 128; off > 0; off >>= 1) {
        if (t < off) red[t] += red[t + off];
        __syncthreads();
    }
    if (t == 0) partial[blockIdx.x] = red[0];
}

__global__ void scan_partials(int* __restrict__ partial, int nb, int* __restrict__ row_ptr, int n) {
    __shared__ int s[256];
    int t = threadIdx.x;
    int v = (t < nb) ? partial[t] : 0;
    s[t] = v;
    __syncthreads();
    #pragma unroll
    for (int off = 1; off < 256; off <<= 1) {
        int u = (t >= off) ? s[t - off] : 0;
        __syncthreads();
        s[t] += u;
        __syncthreads();
    }
    if (t < nb) partial[t] = s[t] - v;
    if (t == 0) row_ptr[n] = s[255];
}

__global__ void scan_final(const int* __restrict__ counts, int n, const int* __restrict__ partial,
                           int* __restrict__ row_ptr, float* __restrict__ dinv,
                           int* __restrict__ fill) {
    __shared__ int s[256];
    int t = threadIdx.x;
    int i = blockIdx.x * 256 + t;
    int c = (i < n) ? counts[i] : 0;
    s[t] = c;
    __syncthreads();
    #pragma unroll
    for (int off = 1; off < 256; off <<= 1) {
        int u = (t >= off) ? s[t - off] : 0;
        __syncthreads();
        s[t] += u;
        __syncthreads();
    }
    if (i < n) {
        row_ptr[i] = partial[blockIdx.x] + s[t] - c;
        dinv[i] = rsqrtf((float)(c + 1));
        fill[i] = 0;
    }
}

__global__ void build_csr(const int* __restrict__ src, const int* __restrict__ dst, int E,
                          const int* __restrict__ row_ptr, int* __restrict__ fill,
                          int2* __restrict__ esw, const float* __restrict__ dinv) {
    int i = blockIdx.x * blockDim.x + threadIdx.x;
    if (i < E) {
        int d = dst[i];
        int s = src[i];
        int pos = row_ptr[d] + atomicAdd(&fill[d], 1);
        esw[pos] = make_int2(s, __float_as_int(dinv[s]));
    }
}

// ---------------- weight split+transpose (all 5 layers, one launch) ----------------
struct SplitArgs {
    const float* W[5];
    _Float16* Wh[5];
    _Float16* Wl[5];
    int lgFI[5];
    int FO[5];
    int off[6];
};

__global__ void split_all(SplitArgs a) {
    int i = blockIdx.x * 256 + threadIdx.x;
    #pragma unroll
    for (int l = 0; l < 5; ++l) {
        if (i >= a.off[l] && i < a.off[l + 1]) {
            int j = i - a.off[l];
            int FI = 1 << a.lgFI[l];
            int c = j >> a.lgFI[l];
            int k = j & (FI - 1);
            float v = a.W[l][(size_t)k * a.FO[l] + c];
            _Float16 h = (_Float16)v;
            a.Wh[l][j] = h;
            a.Wl[l][j] = (_Float16)(v - (float)h);
        }
    }
}

// ---------------- sliced aggregation ----------------
__device__ __forceinline__ float pk2f(uint32_t u) {
    _Float16 h = __builtin_bit_cast(_Float16, (uint16_t)(u & 0xffffu));
    _Float16 l = __builtin_bit_cast(_Float16, (uint16_t)(u >> 16));
    return (float)h + (float)l;
}

// Packed input [n][256] u32, 16 slices x 16 features (64B). Out: hi/lo planes.
// bid = rowchunk*16 + slice; 4 waves x 8 rows per block.
__global__ __launch_bounds__(256) void agg_sliced_packed(
    const uint32_t* __restrict__ inP, const int* __restrict__ row_ptr,
    const int2* __restrict__ esw, const float* __restrict__ dinv,
    _Float16* __restrict__ outH, _Float16* __restrict__ outL, int n) {
    const int bid = blockIdx.x;
    const int slice = bid & 15;
    const int rc = bid >> 4;
    const int w = threadIdx.x >> 6, lane = threadIdx.x & 63;
    const int g = lane >> 3, li = lane & 7;  // 8 groups x 8 lanes, 2 feats/lane
    const uint32_t* sb = inP + slice * 16 + li * 2;
    const int row0 = rc * 32 + w * 8;
    for (int rr = 0; rr < 8; ++rr) {
        const int row = row0 + rr;
        if (row >= n) return;
        const float dd = dinv[row];
        const int e0 = __builtin_amdgcn_readfirstlane(row_ptr[row]);
        const int end = __builtin_amdgcn_readfirstlane(row_ptr[row + 1]);
        float a0, a1;
        {
            uint2 v = *(const uint2*)(sb + (size_t)row * 256);
            const float ws = (g == 0) ? dd : 0.f;
            a0 = ws * pk2f(v.x);
            a1 = ws * pk2f(v.y);
        }
        for (int e = e0; e < end; e += 8) {
            const int ei = e + g;
            const int eic = (ei < end) ? ei : end - 1;
            const int2 q = esw[eic];
            const float wv = (ei < end) ? __int_as_float(q.y) : 0.f;
            const uint2 v = *(const uint2*)(sb + (size_t)q.x * 256);
            a0 += wv * pk2f(v.x);
            a1 += wv * pk2f(v.y);
        }
        #pragma unroll
        for (int off = 8; off < 64; off <<= 1) {
            a0 += __shfl_xor(a0, off);
            a1 += __shfl_xor(a1, off);
        }
        if (g == 0) {
            const float s0 = dd * a0, s1 = dd * a1;
            const _Float16 h0 = (_Float16)s0, h1 = (_Float16)s1;
            const size_t o = (size_t)row * 256 + slice * 16 + li * 2;
            *(v2h*)&outH[o] = (v2h){h0, h1};
            *(v2h*)&outL[o] = (v2h){(_Float16)(s0 - (float)h0), (_Float16)(s1 - (float)h1)};
        }
    }
}

// f32 input [n][F], NSLICE slices x 16 floats (64B).
// SPLIT_OUT: hi/lo planes. else: f32 + bias.
template <int F, int NSLICE, bool SPLIT_OUT>
__global__ __launch_bounds__(256) void agg_sliced_f32(
    const float* __restrict__ in, const int* __restrict__ row_ptr,
    const int2* __restrict__ esw, const float* __restrict__ dinv,
    const float* __restrict__ bias,
    _Float16* __restrict__ outH, _Float16* __restrict__ outL,
    float* __restrict__ outF, int n) {
    const int bid = blockIdx.x;
    const int slice = bid & (NSLICE - 1);
    const int rc = bid / NSLICE;
    const int w = threadIdx.x >> 6, lane = threadIdx.x & 63;
    const int g = lane >> 3, li = lane & 7;
    const float* sb = in + slice * 16 + li * 2;
    const int row0 = rc * 32 + w * 8;
    for (int rr = 0; rr < 8; ++rr) {
        const int row = row0 + rr;
        if (row >= n) return;
        const float dd = dinv[row];
        const int e0 = __builtin_amdgcn_readfirstlane(row_ptr[row]);
        const int end = __builtin_amdgcn_readfirstlane(row_ptr[row + 1]);
        float a0, a1;
        {
            const float2 v = *(const float2*)(sb + (size_t)row * F);
            const float ws = (g == 0) ? dd : 0.f;
            a0 = ws * v.x;
            a1 = ws * v.y;
        }
        for (int e = e0; e < end; e += 8) {
            const int ei = e + g;
            const int eic = (ei < end) ? ei : end - 1;
            const int2 q = esw[eic];
            const float wv = (ei < end) ? __int_as_float(q.y) : 0.f;
            const float2 v = *(const float2*)(sb + (size_t)q.x * F);
            a0 += wv * v.x;
            a1 += wv * v.y;
        }
        #pragma unroll
        for (int off = 8; off < 64; off <<= 1) {
            a0 += __shfl_xor(a0, off);
            a1 += __shfl_xor(a1, off);
        }
        if (g == 0) {
            const int c0 = slice * 16 + li * 2;
            if constexpr (SPLIT_OUT) {
                const float s0 = dd * a0, s1 = dd * a1;
                const _Float16 h0 = (_Float16)s0, h1 = (_Float16)s1;
                const size_t o = (size_t)row * F + c0;
                *(v2h*)&outH[o] = (v2h){h0, h1};
                *(v2h*)&outL[o] = (v2h){(_Float16)(s0 - (float)h0), (_Float16)(s1 - (float)h1)};
            } else {
                float2 r;
                r.x = dd * a0 + bias[c0];
                r.y = dd * a1 + bias[c0 + 1];
                *(float2*)&outF[(size_t)row * F + c0] = r;
            }
        }
    }
}

// ---------------- f16x3 MFMA GEMM ----------------
__device__ __forceinline__ void gl_lds16(const _Float16* g, _Float16* l) {
    __builtin_amdgcn_global_load_lds(
        (const __attribute__((address_space(1))) uint32_t*)g,
        (__attribute__((address_space(3))) uint32_t*)l, 16, 0, 0);
}

// Wide GEMM: out[n x 256] = A[n x FI] @ Wt^T (+bias, relu).  BM=64, BN=256,
// BK=32, 4 waves, 32x32x16 fragments (verified R8, absmax 6e-5).
template <int FI, int OUTMODE>
__global__ __launch_bounds__(256) void gemm_wide(
    const _Float16* __restrict__ Ah, const _Float16* __restrict__ Al,
    const _Float16* __restrict__ Wth, const _Float16* __restrict__ Wtl,  // [256][FI]
    const float* __restrict__ bias,
    uint32_t* __restrict__ Opk, _Float16* __restrict__ Oh, _Float16* __restrict__ Ol,
    int n) {
    constexpr int BK = 32;
    constexpr int NSTEP = FI / BK;
    __shared__ _Float16 lds[20480];
    const int m0 = blockIdx.x * 64;
    const int t = threadIdx.x;
    const int w = t >> 6;
    const int lane = t & 63;

    const int arow = w * 16 + (lane & 15);
    const int akc = (lane >> 4) * 8;
    const _Float16* sAh = Ah + (size_t)(m0 + arow) * FI + akc;
    const _Float16* sAl = Al + (size_t)(m0 + arow) * FI + akc;
    _Float16* dAh = &lds[w * 512];
    _Float16* dAl = &lds[2048 + w * 512];
    size_t boff[4];
    #pragma unroll
    for (int q = 0; q < 4; ++q)
        boff[q] = (size_t)((w * 4 + q) * 16 + (lane & 15)) * FI + akc;

    v16f acc[2][2];
    #pragma unroll
    for (int i = 0; i < 2; ++i)
        #pragma unroll
        for (int j = 0; j < 2; ++j) acc[i][j] = (v16f)(0.f);

    const int rsel = (lane >> 4) & 1;
    const int kq = lane >> 5;
    const int l8 = (lane & 15) * 8;

    for (int s = 0; s < NSTEP; ++s) {
        const int ko = s * BK;
        gl_lds16(sAh + ko, dAh);
        gl_lds16(sAl + ko, dAl);
        #pragma unroll
        for (int q = 0; q < 4; ++q) {
            gl_lds16(Wth + boff[q] + ko, &lds[4096 + (w * 4 + q) * 512]);
            gl_lds16(Wtl + boff[q] + ko, &lds[12288 + (w * 4 + q) * 512]);
        }
        __syncthreads();
        v8h ah[2][2], al[2][2], bh[2][2], bl[2][2];
        #pragma unroll
        for (int i = 0; i < 2; ++i)
            #pragma unroll
            for (int ks = 0; ks < 2; ++ks) {
                const int aoff = (i * 2 + rsel) * 512 + (ks * 2 + kq) * 128 + l8;
                ah[i][ks] = *(const v8h*)&lds[aoff];
                al[i][ks] = *(const v8h*)&lds[2048 + aoff];
            }
        #pragma unroll
        for (int j = 0; j < 2; ++j)
            #pragma unroll
            for (int ks = 0; ks < 2; ++ks) {
                const int bo = 4096 + (w * 4 + j * 2 + rsel) * 512 + (ks * 2 + kq) * 128 + l8;
                bh[j][ks] = *(const v8h*)&lds[bo];
                bl[j][ks] = *(const v8h*)&lds[bo + 8192];
            }
        #pragma unroll
        for (int i = 0; i < 2; ++i)
            #pragma unroll
            for (int j = 0; j < 2; ++j)
                #pragma unroll
                for (int ks = 0; ks < 2; ++ks) {
                    acc[i][j] = __builtin_amdgcn_mfma_f32_32x32x16_f16(ah[i][ks], bh[j][ks], acc[i][j], 0, 0, 0);
                    acc[i][j] = __builtin_amdgcn_mfma_f32_32x32x16_f16(ah[i][ks], bl[j][ks], acc[i][j], 0, 0, 0);
                    acc[i][j] = __builtin_amdgcn_mfma_f32_32x32x16_f16(al[i][ks], bh[j][ks], acc[i][j], 0, 0, 0);
                }
        __syncthreads();
    }

    const int col = lane & 31;
    const int rb4 = (lane >> 5) * 4;
    #pragma unroll
    for (int j = 0; j < 2; ++j) {
        const int gcol = w * 64 + j * 32 + col;
        const float bv = bias[gcol];
        #pragma unroll
        for (int i = 0; i < 2; ++i) {
            #pragma unroll
            for (int reg = 0; reg < 16; ++reg) {
                const int row = (reg & 3) + 8 * (reg >> 2) + rb4;
                const int grow = m0 + i * 32 + row;
                if (grow < n) {
                    float v = fmaxf(acc[i][j][reg] + bv, 0.f);
                    _Float16 h = (_Float16)v;
                    _Float16 l = (_Float16)(v - (float)h);
                    if (OUTMODE == 0) {
                        uint32_t u = (uint32_t)__builtin_bit_cast(uint16_t, h) |
                                     ((uint32_t)__builtin_bit_cast(uint16_t, l) << 16);
                        Opk[(size_t)grow * 256 + gcol] = u;
                    } else {
                        Oh[(size_t)grow * 256 + gcol] = h;
                        Ol[(size_t)grow * 256 + gcol] = l;
                    }
                }
            }
        }
    }
}

// Narrow GEMM for L5: out[n x 64] f32 = A[n x 256] @ Wt^T, no bias/relu.
__global__ __launch_bounds__(256) void gemm_narrow(
    const _Float16* __restrict__ Ah, const _Float16* __restrict__ Al,
    const _Float16* __restrict__ Wth, const _Float16* __restrict__ Wtl,  // [64][256]
    float* __restrict__ Of, int n) {
    constexpr int FI = 256, FO = 64;
    __shared__ _Float16 lds[12288];
    const int m0 = blockIdx.x * 128;
    const int t = threadIdx.x;
    const int w = t >> 6;
    const int lane = t & 63;

    const int G0 = w * 128 + lane;
    const int G1 = G0 + 64;
    const int arow0 = (G0 >> 6) * 16 + (G0 & 15), akc0 = ((G0 >> 4) & 3) * 8;
    const int arow1 = (G1 >> 6) * 16 + (G1 & 15), akc1 = ((G1 >> 4) & 3) * 8;
    const _Float16* sAh0 = Ah + (size_t)(m0 + arow0) * FI + akc0;
    const _Float16* sAh1 = Ah + (size_t)(m0 + arow1) * FI + akc1;
    const _Float16* sAl0 = Al + (size_t)(m0 + arow0) * FI + akc0;
    const _Float16* sAl1 = Al + (size_t)(m0 + arow1) * FI + akc1;
    const int bcol = w * 16 + (lane & 15), bkc = (lane >> 4) * 8;
    const _Float16* sBh = Wth + (size_t)bcol * FI + bkc;
    const _Float16* sBl = Wtl + (size_t)bcol * FI + bkc;

    _Float16* dAh0 = &lds[w * 1024];
    _Float16* dAh1 = &lds[w * 1024 + 512];
    _Float16* dAl0 = &lds[4096 + w * 1024];
    _Float16* dAl1 = &lds[4096 + w * 1024 + 512];
    _Float16* dBh = &lds[8192 + w * 512];
    _Float16* dBl = &lds[10240 + w * 512];

    const int wm = w >> 1, wn = w & 1;
    v4f acc[4][2];
    #pragma unroll
    for (int i = 0; i < 4; ++i)
        #pragma unroll
        for (int j = 0; j < 2; ++j) acc[i][j] = (v4f){0.f, 0.f, 0.f, 0.f};

    for (int s = 0; s < 8; ++s) {
        const int ko = s * 32;
        gl_lds16(sAh0 + ko, dAh0);
        gl_lds16(sAh1 + ko, dAh1);
        gl_lds16(sAl0 + ko, dAl0);
        gl_lds16(sAl1 + ko, dAl1);
        gl_lds16(sBh + ko, dBh);
        gl_lds16(sBl + ko, dBl);
        __syncthreads();
        v8h ah[4], al[4], bh[2], bl[2];
        #pragma unroll
        for (int i = 0; i < 4; ++i) {
            ah[i] = *(const v8h*)&lds[(wm * 4 + i) * 512 + lane * 8];
            al[i] = *(const v8h*)&lds[4096 + (wm * 4 + i) * 512 + lane * 8];
        }
        #pragma unroll
        for (int j = 0; j < 2; ++j) {
            bh[j] = *(const v8h*)&lds[8192 + (wn * 2 + j) * 512 + lane * 8];
            bl[j] = *(const v8h*)&lds[10240 + (wn * 2 + j) * 512 + lane * 8];
        }
        #pragma unroll
        for (int i = 0; i < 4; ++i)
            #pragma unroll
            for (int j = 0; j < 2; ++j) {
                acc[i][j] = __builtin_amdgcn_mfma_f32_16x16x32_f16(ah[i], bh[j], acc[i][j], 0, 0, 0);
                acc[i][j] = __builtin_amdgcn_mfma_f32_16x16x32_f16(ah[i], bl[j], acc[i][j], 0, 0, 0);
                acc[i][j] = __builtin_amdgcn_mfma_f32_16x16x32_f16(al[i], bh[j], acc[i][j], 0, 0, 0);
            }
        __syncthreads();
    }

    const int rl = (lane >> 4) * 4;
    const int cl = lane & 15;
    #pragma unroll
    for (int j = 0; j < 2; ++j) {
        const int gcol = wn * 32 + j * 16 + cl;
        #pragma unroll
        for (int i = 0; i < 4; ++i) {
            const int grow = m0 + wm * 64 + i * 16 + rl;
            #pragma unroll
            for (int r = 0; r < 4; ++r)
                if (grow + r < n) Of[(size_t)(grow + r) * FO + gcol] = acc[i][j][r];
        }
    }
}

// ---------------- launcher ----------------
extern "C" void kernel_launch(void* const* d_in, const int* in_sizes, int n_in,
                              void* d_out, int out_size, void* d_ws, size_t ws_size,
                              hipStream_t stream) {
    const float* x = (const float*)d_in[0];
    const int* ei = (const int*)d_in[1];
    const int E = in_sizes[1] / 2;
    const int n = in_sizes[0] / 128;
    const int* esrc = ei;
    const int* edst = ei + E;
    const float* b[5] = {(const float*)d_in[3], (const float*)d_in[5], (const float*)d_in[7],
                         (const float*)d_in[9], (const float*)d_in[11]};
    float* out = (float*)d_out;
    const int NPAD = ((n + 127) / 128) * 128;

    char* ws = (char*)d_ws;
    auto carve = [&](size_t bytes) {
        char* p = ws;
        ws += (bytes + 255) & ~(size_t)255;
        return p;
    };
    int* counts = (int*)carve((size_t)n * 4);
    int* row_ptr = (int*)carve((size_t)(n + 1) * 4);
    int* fill = (int*)carve((size_t)n * 4);
    float* dinv = (float*)carve((size_t)n * 4);
    int* partial = (int*)carve(1024);
    int2* esw = (int2*)carve((size_t)E * 8);
    const int FIs[5] = {128, 256, 256, 256, 256};
    const int FOs[5] = {256, 256, 256, 256, 64};
    _Float16 *Wh[5], *Wl[5];
    for (int l = 0; l < 5; ++l) {
        Wh[l] = (_Float16*)carve((size_t)FIs[l] * FOs[l] * 2);
        Wl[l] = (_Float16*)carve((size_t)FIs[l] * FOs[l] * 2);
    }
    _Float16* Ah = (_Float16*)carve((size_t)NPAD * 256 * 2);
    _Float16* Al = (_Float16*)carve((size_t)NPAD * 256 * 2);
    uint32_t* Ppk = (uint32_t*)carve((size_t)NPAD * 256 * 4);
    _Float16* Bh2 = (_Float16*)Ppk;                    // L4 planes out (aliases Ppk)
    _Float16* Bl2 = (_Float16*)Ppk + (size_t)NPAD * 256;
    float* scratch = (float*)Ah;                       // L5 gemm f32 out (n x 64)

    hipMemsetAsync(counts, 0, (size_t)n * 4, stream);
    count_edges<<<(E + 255) / 256, 256, 0, stream>>>(edst, E, counts);
    const int nsb = (n + 255) / 256;
    block_sums<<<nsb, 256, 0, stream>>>(counts, n, partial);
    scan_partials<<<1, 256, 0, stream>>>(partial, nsb, row_ptr, n);
    scan_final<<<nsb, 256, 0, stream>>>(counts, n, partial, row_ptr, dinv, fill);
    build_csr<<<(E + 255) / 256, 256, 0, stream>>>(esrc, edst, E, row_ptr, fill, esw, dinv);

    SplitArgs sa;
    int off = 0;
    for (int l = 0; l < 5; ++l) {
        sa.W[l] = (const float*)d_in[2 + 2 * l];
        sa.Wh[l] = Wh[l];
        sa.Wl[l] = Wl[l];
        sa.lgFI[l] = (FIs[l] == 128) ? 7 : 8;
        sa.FO[l] = FOs[l];
        sa.off[l] = off;
        off += FIs[l] * FOs[l];
    }
    sa.off[5] = off;
    split_all<<<(off + 255) / 256, 256, 0, stream>>>(sa);

    const int rcCnt = (n + 31) / 32;  // 32 rows per block (4 waves x 8)
    const int gw = NPAD / 64;   // gemm_wide grid (BM=64)
    const int gn = NPAD / 128;  // gemm_narrow grid

    // L1: sliced agg of x (8 slices) -> planes; gemm 128->256 -> packed
    agg_sliced_f32<128, 8, true><<<rcCnt * 8, 256, 0, stream>>>(
        x, row_ptr, esw, dinv, nullptr, Ah, Al, nullptr, n);
    gemm_wide<128, 0><<<gw, 256, 0, stream>>>(Ah, Al, Wh[0], Wl[0], b[0], Ppk, nullptr, nullptr, n);
    // L2, L3: sliced packed agg (16 slices) -> planes; gemm -> packed
    for (int l = 1; l <= 2; ++l) {
        agg_sliced_packed<<<rcCnt * 16, 256, 0, stream>>>(Ppk, row_ptr, esw, dinv, Ah, Al, n);
        gemm_wide<256, 0><<<gw, 256, 0, stream>>>(Ah, Al, Wh[l], Wl[l], b[l], Ppk, nullptr, nullptr, n);
    }
    // L4 -> planes
    agg_sliced_packed<<<rcCnt * 16, 256, 0, stream>>>(Ppk, row_ptr, esw, dinv, Ah, Al, n);
    gemm_wide<256, 1><<<gw, 256, 0, stream>>>(Ah, Al, Wh[3], Wl[3], b[3], nullptr, Bh2, Bl2, n);
    // L5: narrow gemm -> f32 scratch; sliced agg (4 slices) + bias -> out
    gemm_narrow<<<gn, 256, 0, stream>>>(Bh2, Bl2, Wh[4], Wl[4], scratch, n);
    agg_sliced_f32<64, 4, false><<<rcCnt * 4, 256, 0, stream>>>(
        scratch, row_ptr, esw, dinv, b[4], nullptr, nullptr, out, n);
}

// Round 10
// 669.217 us; speedup vs baseline: 1.8339x; 1.8339x over previous
//
#include <hip/hip_runtime.h>
#include <stdint.h>

// ---------------------------------------------------------------------------
// GCN 5-layer, N=50000, E=600000.  out = ((Anorm @ h) @ W) + b per layer.
// Activations: f16 hi/lo (22-bit mantissa). Packed (h,l) pairs for the agg
// gather (1KB/row contiguous = byte-optimal; 97us/308MB = random-gather BW
// ceiling, confirmed across R3-R9 variants). Hi/lo planes for GEMM staging.
// R6: no fusion. R7: BM=64>128. R8: 32x32x16 frags. R9: NO slicing.
// R10: GEMM K-loop double-buffered (T3 2-phase: stage s+1 || compute s,
// ONE barrier/step instead of two).
// ---------------------------------------------------------------------------

typedef _Float16 v8h __attribute__((ext_vector_type(8)));
typedef _Float16 v4h __attribute__((ext_vector_type(4)));
typedef _Float16 v2h __attribute__((ext_vector_type(2)));
typedef float v4f __attribute__((ext_vector_type(4)));
typedef float v16f __attribute__((ext_vector_type(16)));

// ---------------- CSR build ----------------
__global__ void count_edges(const int* __restrict__ dst, int E, int* __restrict__ counts) {
    int i = blockIdx.x * blockDim.x + threadIdx.x;
    if (i < E) atomicAdd(&counts[dst[i]], 1);
}

__global__ void block_sums(const int* __restrict__ counts, int n, int* __restrict__ partial) {
    __shared__ int red[256];
    int t = threadIdx.x;
    int i = blockIdx.x * 256 + t;
    red[t] = (i < n) ? counts[i] : 0;
    __syncthreads();
    #pragma unroll
    for (int off = 128; off > 0; off >>= 1) {
        if (t < off) red[t] += red[t + off];
        __syncthreads();
    }
    if (t == 0) partial[blockIdx.x] = red[0];
}

__global__ void scan_partials(int* __restrict__ partial, int nb, int* __restrict__ row_ptr, int n) {
    __shared__ int s[256];
    int t = threadIdx.x;
    int v = (t < nb) ? partial[t] : 0;
    s[t] = v;
    __syncthreads();
    #pragma unroll
    for (int off = 1; off < 256; off <<= 1) {
        int u = (t >= off) ? s[t - off] : 0;
        __syncthreads();
        s[t] += u;
        __syncthreads();
    }
    if (t < nb) partial[t] = s[t] - v;
    if (t == 0) row_ptr[n] = s[255];
}

__global__ void scan_final(const int* __restrict__ counts, int n, const int* __restrict__ partial,
                           int* __restrict__ row_ptr, float* __restrict__ dinv,
                           int* __restrict__ fill) {
    __shared__ int s[256];
    int t = threadIdx.x;
    int i = blockIdx.x * 256 + t;
    int c = (i < n) ? counts[i] : 0;
    s[t] = c;
    __syncthreads();
    #pragma unroll
    for (int off = 1; off < 256; off <<= 1) {
        int u = (t >= off) ? s[t - off] : 0;
        __syncthreads();
        s[t] += u;
        __syncthreads();
    }
    if (i < n) {
        row_ptr[i] = partial[blockIdx.x] + s[t] - c;
        dinv[i] = rsqrtf((float)(c + 1));
        fill[i] = 0;
    }
}

__global__ void build_csr(const int* __restrict__ src, const int* __restrict__ dst, int E,
                          const int* __restrict__ row_ptr, int* __restrict__ fill,
                          int2* __restrict__ esw, const float* __restrict__ dinv) {
    int i = blockIdx.x * blockDim.x + threadIdx.x;
    if (i < E) {
        int d = dst[i];
        int s = src[i];
        int pos = row_ptr[d] + atomicAdd(&fill[d], 1);
        esw[pos] = make_int2(s, __float_as_int(dinv[s]));
    }
}

// ---------------- weight split+transpose (all 5 layers, one launch) ----------------
struct SplitArgs {
    const float* W[5];
    _Float16* Wh[5];
    _Float16* Wl[5];
    int lgFI[5];
    int FO[5];
    int off[6];
};

__global__ void split_all(SplitArgs a) {
    int i = blockIdx.x * 256 + threadIdx.x;
    #pragma unroll
    for (int l = 0; l < 5; ++l) {
        if (i >= a.off[l] && i < a.off[l + 1]) {
            int j = i - a.off[l];
            int FI = 1 << a.lgFI[l];
            int c = j >> a.lgFI[l];
            int k = j & (FI - 1);
            float v = a.W[l][(size_t)k * a.FO[l] + c];
            _Float16 h = (_Float16)v;
            a.Wh[l][j] = h;
            a.Wl[l][j] = (_Float16)(v - (float)h);
        }
    }
}

// ---------------- aggregation: packed-in (L2..L4), F=256 (R8 verified) ----------------
__global__ __launch_bounds__(256) void agg_packed(
    const _Float16* __restrict__ inP, const int* __restrict__ row_ptr,
    const int2* __restrict__ esw, const float* __restrict__ dinv,
    _Float16* __restrict__ outH, _Float16* __restrict__ outL, int n) {
    int wid = (blockIdx.x * blockDim.x + threadIdx.x) >> 6;
    if (wid >= n) return;
    const int lane = threadIdx.x & 63;
    int e = __builtin_amdgcn_readfirstlane(row_ptr[wid]);
    const int end = __builtin_amdgcn_readfirstlane(row_ptr[wid + 1]);
    const float dd = dinv[wid];
    const _Float16* rb = inP + (size_t)lane * 8;
    float a0, a1, a2, a3;
    {
        v8h p = *(const v8h*)(rb + (size_t)wid * 512);
        a0 = dd * ((float)p[0] + (float)p[1]);
        a1 = dd * ((float)p[2] + (float)p[3]);
        a2 = dd * ((float)p[4] + (float)p[5]);
        a3 = dd * ((float)p[6] + (float)p[7]);
    }
#define GTH(q) (*(const v8h*)(rb + (size_t)(q).x * 512))
#define ACC(b, w)                                  \
    a0 += (w) * ((float)(b)[0] + (float)(b)[1]);   \
    a1 += (w) * ((float)(b)[2] + (float)(b)[3]);   \
    a2 += (w) * ((float)(b)[4] + (float)(b)[5]);   \
    a3 += (w) * ((float)(b)[6] + (float)(b)[7]);
    for (; e + 8 <= end; e += 8) {
        int2 q0 = esw[e + 0], q1 = esw[e + 1], q2 = esw[e + 2], q3 = esw[e + 3];
        int2 q4 = esw[e + 4], q5 = esw[e + 5], q6 = esw[e + 6], q7 = esw[e + 7];
        v8h b0 = GTH(q0), b1 = GTH(q1), b2 = GTH(q2), b3 = GTH(q3);
        v8h b4 = GTH(q4), b5 = GTH(q5), b6 = GTH(q6), b7 = GTH(q7);
        ACC(b0, __int_as_float(q0.y)) ACC(b1, __int_as_float(q1.y))
        ACC(b2, __int_as_float(q2.y)) ACC(b3, __int_as_float(q3.y))
        ACC(b4, __int_as_float(q4.y)) ACC(b5, __int_as_float(q5.y))
        ACC(b6, __int_as_float(q6.y)) ACC(b7, __int_as_float(q7.y))
    }
    if (e + 4 <= end) {
        int2 q0 = esw[e + 0], q1 = esw[e + 1], q2 = esw[e + 2], q3 = esw[e + 3];
        v8h b0 = GTH(q0), b1 = GTH(q1), b2 = GTH(q2), b3 = GTH(q3);
        ACC(b0, __int_as_float(q0.y)) ACC(b1, __int_as_float(q1.y))
        ACC(b2, __int_as_float(q2.y)) ACC(b3, __int_as_float(q3.y))
        e += 4;
    }
    if (e < end) {
        const int em = end - 1;
        int e1 = (e + 1 < end) ? e + 1 : em;
        int e2 = (e + 2 < end) ? e + 2 : em;
        int2 q0 = esw[e], q1 = esw[e1], q2 = esw[e2], q3 = esw[em];
        float w0 = __int_as_float(q0.y);
        float w1 = (e + 1 < end) ? __int_as_float(q1.y) : 0.f;
        float w2 = (e + 2 < end) ? __int_as_float(q2.y) : 0.f;
        float w3 = (e + 3 < end) ? __int_as_float(q3.y) : 0.f;
        v8h b0 = GTH(q0), b1 = GTH(q1), b2 = GTH(q2), b3 = GTH(q3);
        ACC(b0, w0) ACC(b1, w1) ACC(b2, w2) ACC(b3, w3)
    }
#undef GTH
#undef ACC
    size_t o = (size_t)wid * 256 + lane * 4;
    float s0 = dd * a0, s1 = dd * a1, s2 = dd * a2, s3 = dd * a3;
    _Float16 h0 = (_Float16)s0, h1 = (_Float16)s1, h2 = (_Float16)s2, h3 = (_Float16)s3;
    *(v4h*)&outH[o] = (v4h){h0, h1, h2, h3};
    *(v4h*)&outL[o] = (v4h){(_Float16)(s0 - (float)h0), (_Float16)(s1 - (float)h1),
                            (_Float16)(s2 - (float)h2), (_Float16)(s3 - (float)h3)};
}

// ---------------- aggregation: f32-in 128 feats (L1) -> hi/lo planes ----------------
__global__ __launch_bounds__(256) void agg_f32_128(
    const float* __restrict__ in, const int* __restrict__ row_ptr,
    const int2* __restrict__ esw, const float* __restrict__ dinv,
    _Float16* __restrict__ outH, _Float16* __restrict__ outL, int n) {
    int wid = (blockIdx.x * blockDim.x + threadIdx.x) >> 6;
    if (wid >= n) return;
    const int lane = threadIdx.x & 63;
    int e = __builtin_amdgcn_readfirstlane(row_ptr[wid]);
    const int end = __builtin_amdgcn_readfirstlane(row_ptr[wid + 1]);
    const float dd = dinv[wid];
    const float* rb = in + (size_t)lane * 2;
    float a0, a1;
    {
        float2 p = *(const float2*)(rb + (size_t)wid * 128);
        a0 = dd * p.x;
        a1 = dd * p.y;
    }
#define GTH(q) (*(const float2*)(rb + (size_t)(q).x * 128))
#define ACC(b, w) a0 += (w) * (b).x; a1 += (w) * (b).y;
    for (; e + 8 <= end; e += 8) {
        int2 q0 = esw[e + 0], q1 = esw[e + 1], q2 = esw[e + 2], q3 = esw[e + 3];
        int2 q4 = esw[e + 4], q5 = esw[e + 5], q6 = esw[e + 6], q7 = esw[e + 7];
        float2 b0 = GTH(q0), b1 = GTH(q1), b2 = GTH(q2), b3 = GTH(q3);
        float2 b4 = GTH(q4), b5 = GTH(q5), b6 = GTH(q6), b7 = GTH(q7);
        ACC(b0, __int_as_float(q0.y)) ACC(b1, __int_as_float(q1.y))
        ACC(b2, __int_as_float(q2.y)) ACC(b3, __int_as_float(q3.y))
        ACC(b4, __int_as_float(q4.y)) ACC(b5, __int_as_float(q5.y))
        ACC(b6, __int_as_float(q6.y)) ACC(b7, __int_as_float(q7.y))
    }
    if (e + 4 <= end) {
        int2 q0 = esw[e + 0], q1 = esw[e + 1], q2 = esw[e + 2], q3 = esw[e + 3];
        float2 b0 = GTH(q0), b1 = GTH(q1), b2 = GTH(q2), b3 = GTH(q3);
        ACC(b0, __int_as_float(q0.y)) ACC(b1, __int_as_float(q1.y))
        ACC(b2, __int_as_float(q2.y)) ACC(b3, __int_as_float(q3.y))
        e += 4;
    }
    if (e < end) {
        const int em = end - 1;
        int e1 = (e + 1 < end) ? e + 1 : em;
        int e2 = (e + 2 < end) ? e + 2 : em;
        int2 q0 = esw[e], q1 = esw[e1], q2 = esw[e2], q3 = esw[em];
        float w0 = __int_as_float(q0.y);
        float w1 = (e + 1 < end) ? __int_as_float(q1.y) : 0.f;
        float w2 = (e + 2 < end) ? __int_as_float(q2.y) : 0.f;
        float w3 = (e + 3 < end) ? __int_as_float(q3.y) : 0.f;
        float2 b0 = GTH(q0), b1 = GTH(q1), b2 = GTH(q2), b3 = GTH(q3);
        ACC(b0, w0) ACC(b1, w1) ACC(b2, w2) ACC(b3, w3)
    }
#undef GTH
#undef ACC
    size_t o = (size_t)wid * 128 + lane * 2;
    float s0 = dd * a0, s1 = dd * a1;
    _Float16 h0 = (_Float16)s0, h1 = (_Float16)s1;
    *(v2h*)&outH[o] = (v2h){h0, h1};
    *(v2h*)&outL[o] = (v2h){(_Float16)(s0 - (float)h0), (_Float16)(s1 - (float)h1)};
}

// ---------------- aggregation: f32-in 64 feats (L5) -> f32 + bias ----------------
__global__ __launch_bounds__(256) void agg_f32_64(
    const float* __restrict__ in, const int* __restrict__ row_ptr,
    const int2* __restrict__ esw, const float* __restrict__ dinv,
    const float* __restrict__ bias, float* __restrict__ outF, int n) {
    int wid = (blockIdx.x * blockDim.x + threadIdx.x) >> 6;
    if (wid >= n) return;
    const int lane = threadIdx.x & 63;
    int e = __builtin_amdgcn_readfirstlane(row_ptr[wid]);
    const int end = __builtin_amdgcn_readfirstlane(row_ptr[wid + 1]);
    const float dd = dinv[wid];
    const float* rb = in + lane;
    float a0 = dd * rb[(size_t)wid * 64];
#define GTH(q) (rb[(size_t)(q).x * 64])
    for (; e + 8 <= end; e += 8) {
        int2 q0 = esw[e + 0], q1 = esw[e + 1], q2 = esw[e + 2], q3 = esw[e + 3];
        int2 q4 = esw[e + 4], q5 = esw[e + 5], q6 = esw[e + 6], q7 = esw[e + 7];
        float b0 = GTH(q0), b1 = GTH(q1), b2 = GTH(q2), b3 = GTH(q3);
        float b4 = GTH(q4), b5 = GTH(q5), b6 = GTH(q6), b7 = GTH(q7);
        a0 += __int_as_float(q0.y) * b0 + __int_as_float(q1.y) * b1;
        a0 += __int_as_float(q2.y) * b2 + __int_as_float(q3.y) * b3;
        a0 += __int_as_float(q4.y) * b4 + __int_as_float(q5.y) * b5;
        a0 += __int_as_float(q6.y) * b6 + __int_as_float(q7.y) * b7;
    }
    if (e + 4 <= end) {
        int2 q0 = esw[e + 0], q1 = esw[e + 1], q2 = esw[e + 2], q3 = esw[e + 3];
        float b0 = GTH(q0), b1 = GTH(q1), b2 = GTH(q2), b3 = GTH(q3);
        a0 += __int_as_float(q0.y) * b0 + __int_as_float(q1.y) * b1;
        a0 += __int_as_float(q2.y) * b2 + __int_as_float(q3.y) * b3;
        e += 4;
    }
    if (e < end) {
        const int em = end - 1;
        int e1 = (e + 1 < end) ? e + 1 : em;
        int e2 = (e + 2 < end) ? e + 2 : em;
        int2 q0 = esw[e], q1 = esw[e1], q2 = esw[e2], q3 = esw[em];
        float w0 = __int_as_float(q0.y);
        float w1 = (e + 1 < end) ? __int_as_float(q1.y) : 0.f;
        float w2 = (e + 2 < end) ? __int_as_float(q2.y) : 0.f;
        float w3 = (e + 3 < end) ? __int_as_float(q3.y) : 0.f;
        float b0 = GTH(q0), b1 = GTH(q1), b2 = GTH(q2), b3 = GTH(q3);
        a0 += w0 * b0 + w1 * b1 + w2 * b2 + w3 * b3;
    }
#undef GTH
    outF[(size_t)wid * 64 + lane] = dd * a0 + bias[lane];
}

// ---------------- f16x3 MFMA GEMM (double-buffered K-loop) ----------------
__device__ __forceinline__ void gl_lds16(const _Float16* g, _Float16* l) {
    __builtin_amdgcn_global_load_lds(
        (const __attribute__((address_space(1))) uint32_t*)g,
        (__attribute__((address_space(3))) uint32_t*)l, 16, 0, 0);
}

// Wide GEMM: out[n x 256] = A[n x FI] @ Wt^T (+bias, relu).  BM=64, BN=256,
// BK=32, 4 waves, 32x32x16 fragments.  Double-buffered: stage(s+1) issued
// after the barrier, overlapping the MFMA of step s; ONE barrier per step.
// Per-buffer LDS (f16): A_hi[0,2048) A_lo[2048,4096) B_hi[4096,12288)
// B_lo[12288,20480); two buffers = 80KB.
template <int FI, int OUTMODE>
__global__ __launch_bounds__(256) void gemm_wide(
    const _Float16* __restrict__ Ah, const _Float16* __restrict__ Al,
    const _Float16* __restrict__ Wth, const _Float16* __restrict__ Wtl,  // [256][FI]
    const float* __restrict__ bias,
    uint32_t* __restrict__ Opk, _Float16* __restrict__ Oh, _Float16* __restrict__ Ol,
    int n) {
    constexpr int BK = 32;
    constexpr int NSTEP = FI / BK;
    constexpr int BUF = 20480;
    __shared__ _Float16 lds[2 * BUF];
    const int m0 = blockIdx.x * 64;
    const int t = threadIdx.x;
    const int w = t >> 6;
    const int lane = t & 63;

    const int arow = w * 16 + (lane & 15);
    const int akc = (lane >> 4) * 8;
    const _Float16* sAh = Ah + (size_t)(m0 + arow) * FI + akc;
    const _Float16* sAl = Al + (size_t)(m0 + arow) * FI + akc;
    size_t boff[4];
    #pragma unroll
    for (int q = 0; q < 4; ++q)
        boff[q] = (size_t)((w * 4 + q) * 16 + (lane & 15)) * FI + akc;

    auto STAGE = [&](int buf, int ko) {
        _Float16* base = &lds[buf * BUF];
        gl_lds16(sAh + ko, base + w * 512);
        gl_lds16(sAl + ko, base + 2048 + w * 512);
        #pragma unroll
        for (int q = 0; q < 4; ++q) {
            gl_lds16(Wth + boff[q] + ko, base + 4096 + (w * 4 + q) * 512);
            gl_lds16(Wtl + boff[q] + ko, base + 12288 + (w * 4 + q) * 512);
        }
    };

    v16f acc[2][2];
    #pragma unroll
    for (int i = 0; i < 2; ++i)
        #pragma unroll
        for (int j = 0; j < 2; ++j) acc[i][j] = (v16f)(0.f);

    const int rsel = (lane >> 4) & 1;
    const int kq = lane >> 5;
    const int l8 = (lane & 15) * 8;

    STAGE(0, 0);
    int cur = 0;
    for (int s = 0; s < NSTEP; ++s) {
        __syncthreads();  // drains vmcnt: buf[cur] resident; prior reads of buf[cur^1] done
        if (s + 1 < NSTEP) STAGE(cur ^ 1, (s + 1) * BK);  // in flight during MFMA below
        const int cb = cur * BUF;
        v8h ah[2][2], al[2][2], bh[2][2], bl[2][2];
        #pragma unroll
        for (int i = 0; i < 2; ++i)
            #pragma unroll
            for (int ks = 0; ks < 2; ++ks) {
                const int aoff = cb + (i * 2 + rsel) * 512 + (ks * 2 + kq) * 128 + l8;
                ah[i][ks] = *(const v8h*)&lds[aoff];
                al[i][ks] = *(const v8h*)&lds[2048 + aoff];
            }
        #pragma unroll
        for (int j = 0; j < 2; ++j)
            #pragma unroll
            for (int ks = 0; ks < 2; ++ks) {
                const int bo = cb + 4096 + (w * 4 + j * 2 + rsel) * 512 + (ks * 2 + kq) * 128 + l8;
                bh[j][ks] = *(const v8h*)&lds[bo];
                bl[j][ks] = *(const v8h*)&lds[bo + 8192];
            }
        #pragma unroll
        for (int i = 0; i < 2; ++i)
            #pragma unroll
            for (int j = 0; j < 2; ++j)
                #pragma unroll
                for (int ks = 0; ks < 2; ++ks) {
                    acc[i][j] = __builtin_amdgcn_mfma_f32_32x32x16_f16(ah[i][ks], bh[j][ks], acc[i][j], 0, 0, 0);
                    acc[i][j] = __builtin_amdgcn_mfma_f32_32x32x16_f16(ah[i][ks], bl[j][ks], acc[i][j], 0, 0, 0);
                    acc[i][j] = __builtin_amdgcn_mfma_f32_32x32x16_f16(al[i][ks], bh[j][ks], acc[i][j], 0, 0, 0);
                }
        cur ^= 1;
    }

    const int col = lane & 31;
    const int rb4 = (lane >> 5) * 4;
    #pragma unroll
    for (int j = 0; j < 2; ++j) {
        const int gcol = w * 64 + j * 32 + col;
        const float bv = bias[gcol];
        #pragma unroll
        for (int i = 0; i < 2; ++i) {
            #pragma unroll
            for (int reg = 0; reg < 16; ++reg) {
                const int row = (reg & 3) + 8 * (reg >> 2) + rb4;
                const int grow = m0 + i * 32 + row;
                if (grow < n) {
                    float v = fmaxf(acc[i][j][reg] + bv, 0.f);
                    _Float16 h = (_Float16)v;
                    _Float16 l = (_Float16)(v - (float)h);
                    if (OUTMODE == 0) {
                        uint32_t u = (uint32_t)__builtin_bit_cast(uint16_t, h) |
                                     ((uint32_t)__builtin_bit_cast(uint16_t, l) << 16);
                        Opk[(size_t)grow * 256 + gcol] = u;
                    } else {
                        Oh[(size_t)grow * 256 + gcol] = h;
                        Ol[(size_t)grow * 256 + gcol] = l;
                    }
                }
            }
        }
    }
}

// Narrow GEMM for L5: out[n x 64] f32, double-buffered like gemm_wide.
// Per-buffer LDS (f16): A 8192 (hi 4096 + lo 4096), B 4096 -> 12288; x2 = 48KB.
__global__ __launch_bounds__(256) void gemm_narrow(
    const _Float16* __restrict__ Ah, const _Float16* __restrict__ Al,
    const _Float16* __restrict__ Wth, const _Float16* __restrict__ Wtl,  // [64][256]
    float* __restrict__ Of, int n) {
    constexpr int FI = 256, FO = 64;
    constexpr int BUF = 12288;
    __shared__ _Float16 lds[2 * BUF];
    const int m0 = blockIdx.x * 128;
    const int t = threadIdx.x;
    const int w = t >> 6;
    const int lane = t & 63;

    const int G0 = w * 128 + lane;
    const int G1 = G0 + 64;
    const int arow0 = (G0 >> 6) * 16 + (G0 & 15), akc0 = ((G0 >> 4) & 3) * 8;
    const int arow1 = (G1 >> 6) * 16 + (G1 & 15), akc1 = ((G1 >> 4) & 3) * 8;
    const _Float16* sAh0 = Ah + (size_t)(m0 + arow0) * FI + akc0;
    const _Float16* sAh1 = Ah + (size_t)(m0 + arow1) * FI + akc1;
    const _Float16* sAl0 = Al + (size_t)(m0 + arow0) * FI + akc0;
    const _Float16* sAl1 = Al + (size_t)(m0 + arow1) * FI + akc1;
    const int bcol = w * 16 + (lane & 15), bkc = (lane >> 4) * 8;
    const _Float16* sBh = Wth + (size_t)bcol * FI + bkc;
    const _Float16* sBl = Wtl + (size_t)bcol * FI + bkc;

    auto STAGE = [&](int buf, int ko) {
        _Float16* base = &lds[buf * BUF];
        gl_lds16(sAh0 + ko, base + w * 1024);
        gl_lds16(sAh1 + ko, base + w * 1024 + 512);
        gl_lds16(sAl0 + ko, base + 4096 + w * 1024);
        gl_lds16(sAl1 + ko, base + 4096 + w * 1024 + 512);
        gl_lds16(sBh + ko, base + 8192 + w * 512);
        gl_lds16(sBl + ko, base + 10240 + w * 512);
    };

    const int wm = w >> 1, wn = w & 1;
    v4f acc[4][2];
    #pragma unroll
    for (int i = 0; i < 4; ++i)
        #pragma unroll
        for (int j = 0; j < 2; ++j) acc[i][j] = (v4f){0.f, 0.f, 0.f, 0.f};

    STAGE(0, 0);
    int cur = 0;
    for (int s = 0; s < 8; ++s) {
        __syncthreads();
        if (s + 1 < 8) STAGE(cur ^ 1, (s + 1) * 32);
        const int cb = cur * BUF;
        v8h ah[4], al[4], bh[2], bl[2];
        #pragma unroll
        for (int i = 0; i < 4; ++i) {
            ah[i] = *(const v8h*)&lds[cb + (wm * 4 + i) * 512 + lane * 8];
            al[i] = *(const v8h*)&lds[cb + 4096 + (wm * 4 + i) * 512 + lane * 8];
        }
        #pragma unroll
        for (int j = 0; j < 2; ++j) {
            bh[j] = *(const v8h*)&lds[cb + 8192 + (wn * 2 + j) * 512 + lane * 8];
            bl[j] = *(const v8h*)&lds[cb + 10240 + (wn * 2 + j) * 512 + lane * 8];
        }
        #pragma unroll
        for (int i = 0; i < 4; ++i)
            #pragma unroll
            for (int j = 0; j < 2; ++j) {
                acc[i][j] = __builtin_amdgcn_mfma_f32_16x16x32_f16(ah[i], bh[j], acc[i][j], 0, 0, 0);
                acc[i][j] = __builtin_amdgcn_mfma_f32_16x16x32_f16(ah[i], bl[j], acc[i][j], 0, 0, 0);
                acc[i][j] = __builtin_amdgcn_mfma_f32_16x16x32_f16(al[i], bh[j], acc[i][j], 0, 0, 0);
            }
        cur ^= 1;
    }

    const int rl = (lane >> 4) * 4;
    const int cl = lane & 15;
    #pragma unroll
    for (int j = 0; j < 2; ++j) {
        const int gcol = wn * 32 + j * 16 + cl;
        #pragma unroll
        for (int i = 0; i < 4; ++i) {
            const int grow = m0 + wm * 64 + i * 16 + rl;
            #pragma unroll
            for (int r = 0; r < 4; ++r)
                if (grow + r < n) Of[(size_t)(grow + r) * FO + gcol] = acc[i][j][r];
        }
    }
}

// ---------------- launcher ----------------
extern "C" void kernel_launch(void* const* d_in, const int* in_sizes, int n_in,
                              void* d_out, int out_size, void* d_ws, size_t ws_size,
                              hipStream_t stream) {
    const float* x = (const float*)d_in[0];
    const int* ei = (const int*)d_in[1];
    const int E = in_sizes[1] / 2;
    const int n = in_sizes[0] / 128;
    const int* esrc = ei;
    const int* edst = ei + E;
    const float* b[5] = {(const float*)d_in[3], (const float*)d_in[5], (const float*)d_in[7],
                         (const float*)d_in[9], (const float*)d_in[11]};
    float* out = (float*)d_out;
    const int NPAD = ((n + 127) / 128) * 128;

    char* ws = (char*)d_ws;
    auto carve = [&](size_t bytes) {
        char* p = ws;
        ws += (bytes + 255) & ~(size_t)255;
        return p;
    };
    int* counts = (int*)carve((size_t)n * 4);
    int* row_ptr = (int*)carve((size_t)(n + 1) * 4);
    int* fill = (int*)carve((size_t)n * 4);
    float* dinv = (float*)carve((size_t)n * 4);
    int* partial = (int*)carve(1024);
    int2* esw = (int2*)carve((size_t)E * 8);
    const int FIs[5] = {128, 256, 256, 256, 256};
    const int FOs[5] = {256, 256, 256, 256, 64};
    _Float16 *Wh[5], *Wl[5];
    for (int l = 0; l < 5; ++l) {
        Wh[l] = (_Float16*)carve((size_t)FIs[l] * FOs[l] * 2);
        Wl[l] = (_Float16*)carve((size_t)FIs[l] * FOs[l] * 2);
    }
    _Float16* Ah = (_Float16*)carve((size_t)NPAD * 256 * 2);
    _Float16* Al = (_Float16*)carve((size_t)NPAD * 256 * 2);
    uint32_t* Ppk = (uint32_t*)carve((size_t)NPAD * 256 * 4);
    _Float16* Bh2 = (_Float16*)Ppk;                    // L4 planes out (aliases Ppk)
    _Float16* Bl2 = (_Float16*)Ppk + (size_t)NPAD * 256;
    float* scratch = (float*)Ah;                       // L5 gemm f32 out (n x 64)

    hipMemsetAsync(counts, 0, (size_t)n * 4, stream);
    count_edges<<<(E + 255) / 256, 256, 0, stream>>>(edst, E, counts);
    const int nsb = (n + 255) / 256;
    block_sums<<<nsb, 256, 0, stream>>>(counts, n, partial);
    scan_partials<<<1, 256, 0, stream>>>(partial, nsb, row_ptr, n);
    scan_final<<<nsb, 256, 0, stream>>>(counts, n, partial, row_ptr, dinv, fill);
    build_csr<<<(E + 255) / 256, 256, 0, stream>>>(esrc, edst, E, row_ptr, fill, esw, dinv);

    SplitArgs sa;
    int off = 0;
    for (int l = 0; l < 5; ++l) {
        sa.W[l] = (const float*)d_in[2 + 2 * l];
        sa.Wh[l] = Wh[l];
        sa.Wl[l] = Wl[l];
        sa.lgFI[l] = (FIs[l] == 128) ? 7 : 8;
        sa.FO[l] = FOs[l];
        sa.off[l] = off;
        off += FIs[l] * FOs[l];
    }
    sa.off[5] = off;
    split_all<<<(off + 255) / 256, 256, 0, stream>>>(sa);

    const int aggBlocks = (n + 3) / 4;
    const int gw = NPAD / 64;   // gemm_wide grid (BM=64)
    const int gn = NPAD / 128;  // gemm_narrow grid

    // L1
    agg_f32_128<<<aggBlocks, 256, 0, stream>>>(x, row_ptr, esw, dinv, Ah, Al, n);
    gemm_wide<128, 0><<<gw, 256, 0, stream>>>(Ah, Al, Wh[0], Wl[0], b[0], Ppk, nullptr, nullptr, n);
    // L2, L3
    for (int l = 1; l <= 2; ++l) {
        agg_packed<<<aggBlocks, 256, 0, stream>>>((const _Float16*)Ppk, row_ptr, esw, dinv, Ah, Al, n);
        gemm_wide<256, 0><<<gw, 256, 0, stream>>>(Ah, Al, Wh[l], Wl[l], b[l], Ppk, nullptr, nullptr, n);
    }
    // L4 -> planes
    agg_packed<<<aggBlocks, 256, 0, stream>>>((const _Float16*)Ppk, row_ptr, esw, dinv, Ah, Al, n);
    gemm_wide<256, 1><<<gw, 256, 0, stream>>>(Ah, Al, Wh[3], Wl[3], b[3], nullptr, Bh2, Bl2, n);
    // L5
    gemm_narrow<<<gn, 256, 0, stream>>>(Bh2, Bl2, Wh[4], Wl[4], scratch, n);
    agg_f32_64<<<(n + 3) / 4, 256, 0, stream>>>(scratch, row_ptr, esw, dinv, b[4], out, n);
}

// Round 11
// 635.789 us; speedup vs baseline: 1.9303x; 1.0526x over previous
//
#include <hip/hip_runtime.h>
#include <stdint.h>

// ---------------------------------------------------------------------------
// GCN 5-layer, N=50000, E=600000.  out = ((Anorm @ h) @ W) + b per layer.
// Activations: f16 hi/lo packed (h,l) u32; hi/lo planes for GEMM staging.
// agg: 1KB-row gather = at L3-random ceiling (97us/308MB, R3-R10 confirmed).
// R11: HIDE the GEMMs under agg stalls. Per layer, rows split in half:
//   A_h1  ->  MIX{ gemm(h1) blocks + agg(h2) blocks }  ->  gemm(h2)
// gemm row-block depends only on agg of SAME rows; agg l+1 needs all gemm l.
// MIX = block-specialized single dispatch, no shared barriers (R6 lesson),
// 40KB LDS + launch_bounds(256,4) keeps 4 blocks/CU for the agg blocks.
// P0/P1 ping-pong so MIX gemm-writes never race agg-reads.
// ---------------------------------------------------------------------------

typedef _Float16 v8h __attribute__((ext_vector_type(8)));
typedef _Float16 v4h __attribute__((ext_vector_type(4)));
typedef _Float16 v2h __attribute__((ext_vector_type(2)));
typedef float v4f __attribute__((ext_vector_type(4)));
typedef float v16f __attribute__((ext_vector_type(16)));

// ---------------- CSR build ----------------
__global__ void count_edges(const int* __restrict__ dst, int E, int* __restrict__ counts) {
    int i = blockIdx.x * blockDim.x + threadIdx.x;
    if (i < E) atomicAdd(&counts[dst[i]], 1);
}

__global__ void block_sums(const int* __restrict__ counts, int n, int* __restrict__ partial) {
    __shared__ int red[256];
    int t = threadIdx.x;
    int i = blockIdx.x * 256 + t;
    red[t] = (i < n) ? counts[i] : 0;
    __syncthreads();
    #pragma unroll
    for (int off = 128; off > 0; off >>= 1) {
        if (t < off) red[t] += red[t + off];
        __syncthreads();
    }
    if (t == 0) partial[blockIdx.x] = red[0];
}

__global__ void scan_partials(int* __restrict__ partial, int nb, int* __restrict__ row_ptr, int n) {
    __shared__ int s[256];
    int t = threadIdx.x;
    int v = (t < nb) ? partial[t] : 0;
    s[t] = v;
    __syncthreads();
    #pragma unroll
    for (int off = 1; off < 256; off <<= 1) {
        int u = (t >= off) ? s[t - off] : 0;
        __syncthreads();
        s[t] += u;
        __syncthreads();
    }
    if (t < nb) partial[t] = s[t] - v;
    if (t == 0) row_ptr[n] = s[255];
}

__global__ void scan_final(const int* __restrict__ counts, int n, const int* __restrict__ partial,
                           int* __restrict__ row_ptr, float* __restrict__ dinv,
                           int* __restrict__ fill) {
    __shared__ int s[256];
    int t = threadIdx.x;
    int i = blockIdx.x * 256 + t;
    int c = (i < n) ? counts[i] : 0;
    s[t] = c;
    __syncthreads();
    #pragma unroll
    for (int off = 1; off < 256; off <<= 1) {
        int u = (t >= off) ? s[t - off] : 0;
        __syncthreads();
        s[t] += u;
        __syncthreads();
    }
    if (i < n) {
        row_ptr[i] = partial[blockIdx.x] + s[t] - c;
        dinv[i] = rsqrtf((float)(c + 1));
        fill[i] = 0;
    }
}

__global__ void build_csr(const int* __restrict__ src, const int* __restrict__ dst, int E,
                          const int* __restrict__ row_ptr, int* __restrict__ fill,
                          int2* __restrict__ esw, const float* __restrict__ dinv) {
    int i = blockIdx.x * blockDim.x + threadIdx.x;
    if (i < E) {
        int d = dst[i];
        int s = src[i];
        int pos = row_ptr[d] + atomicAdd(&fill[d], 1);
        esw[pos] = make_int2(s, __float_as_int(dinv[s]));
    }
}

// ---------------- weight split+transpose ----------------
struct SplitArgs {
    const float* W[5];
    _Float16* Wh[5];
    _Float16* Wl[5];
    int lgFI[5];
    int FO[5];
    int off[6];
};

__global__ void split_all(SplitArgs a) {
    int i = blockIdx.x * 256 + threadIdx.x;
    #pragma unroll
    for (int l = 0; l < 5; ++l) {
        if (i >= a.off[l] && i < a.off[l + 1]) {
            int j = i - a.off[l];
            int FI = 1 << a.lgFI[l];
            int c = j >> a.lgFI[l];
            int k = j & (FI - 1);
            float v = a.W[l][(size_t)k * a.FO[l] + c];
            _Float16 h = (_Float16)v;
            a.Wh[l][j] = h;
            a.Wl[l][j] = (_Float16)(v - (float)h);
        }
    }
}

// ---------------- agg row bodies (device) ----------------
__device__ __forceinline__ void agg_packed_row(
    int wid, int lane, const _Float16* __restrict__ inP, const int* __restrict__ row_ptr,
    const int2* __restrict__ esw, const float* __restrict__ dinv,
    _Float16* __restrict__ outH, _Float16* __restrict__ outL) {
    int e = __builtin_amdgcn_readfirstlane(row_ptr[wid]);
    const int end = __builtin_amdgcn_readfirstlane(row_ptr[wid + 1]);
    const float dd = dinv[wid];
    const _Float16* rb = inP + (size_t)lane * 8;
    float a0, a1, a2, a3;
    {
        v8h p = *(const v8h*)(rb + (size_t)wid * 512);
        a0 = dd * ((float)p[0] + (float)p[1]);
        a1 = dd * ((float)p[2] + (float)p[3]);
        a2 = dd * ((float)p[4] + (float)p[5]);
        a3 = dd * ((float)p[6] + (float)p[7]);
    }
#define GTH(q) (*(const v8h*)(rb + (size_t)(q).x * 512))
#define ACC(b, w)                                  \
    a0 += (w) * ((float)(b)[0] + (float)(b)[1]);   \
    a1 += (w) * ((float)(b)[2] + (float)(b)[3]);   \
    a2 += (w) * ((float)(b)[4] + (float)(b)[5]);   \
    a3 += (w) * ((float)(b)[6] + (float)(b)[7]);
    for (; e + 8 <= end; e += 8) {
        int2 q0 = esw[e + 0], q1 = esw[e + 1], q2 = esw[e + 2], q3 = esw[e + 3];
        int2 q4 = esw[e + 4], q5 = esw[e + 5], q6 = esw[e + 6], q7 = esw[e + 7];
        v8h b0 = GTH(q0), b1 = GTH(q1), b2 = GTH(q2), b3 = GTH(q3);
        v8h b4 = GTH(q4), b5 = GTH(q5), b6 = GTH(q6), b7 = GTH(q7);
        ACC(b0, __int_as_float(q0.y)) ACC(b1, __int_as_float(q1.y))
        ACC(b2, __int_as_float(q2.y)) ACC(b3, __int_as_float(q3.y))
        ACC(b4, __int_as_float(q4.y)) ACC(b5, __int_as_float(q5.y))
        ACC(b6, __int_as_float(q6.y)) ACC(b7, __int_as_float(q7.y))
    }
    if (e + 4 <= end) {
        int2 q0 = esw[e + 0], q1 = esw[e + 1], q2 = esw[e + 2], q3 = esw[e + 3];
        v8h b0 = GTH(q0), b1 = GTH(q1), b2 = GTH(q2), b3 = GTH(q3);
        ACC(b0, __int_as_float(q0.y)) ACC(b1, __int_as_float(q1.y))
        ACC(b2, __int_as_float(q2.y)) ACC(b3, __int_as_float(q3.y))
        e += 4;
    }
    if (e < end) {
        const int em = end - 1;
        int e1 = (e + 1 < end) ? e + 1 : em;
        int e2 = (e + 2 < end) ? e + 2 : em;
        int2 q0 = esw[e], q1 = esw[e1], q2 = esw[e2], q3 = esw[em];
        float w0 = __int_as_float(q0.y);
        float w1 = (e + 1 < end) ? __int_as_float(q1.y) : 0.f;
        float w2 = (e + 2 < end) ? __int_as_float(q2.y) : 0.f;
        float w3 = (e + 3 < end) ? __int_as_float(q3.y) : 0.f;
        v8h b0 = GTH(q0), b1 = GTH(q1), b2 = GTH(q2), b3 = GTH(q3);
        ACC(b0, w0) ACC(b1, w1) ACC(b2, w2) ACC(b3, w3)
    }
#undef GTH
#undef ACC
    size_t o = (size_t)wid * 256 + lane * 4;
    float s0 = dd * a0, s1 = dd * a1, s2 = dd * a2, s3 = dd * a3;
    _Float16 h0 = (_Float16)s0, h1 = (_Float16)s1, h2 = (_Float16)s2, h3 = (_Float16)s3;
    *(v4h*)&outH[o] = (v4h){h0, h1, h2, h3};
    *(v4h*)&outL[o] = (v4h){(_Float16)(s0 - (float)h0), (_Float16)(s1 - (float)h1),
                            (_Float16)(s2 - (float)h2), (_Float16)(s3 - (float)h3)};
}

__device__ __forceinline__ void agg_f128_row(
    int wid, int lane, const float* __restrict__ in, const int* __restrict__ row_ptr,
    const int2* __restrict__ esw, const float* __restrict__ dinv,
    _Float16* __restrict__ outH, _Float16* __restrict__ outL) {
    int e = __builtin_amdgcn_readfirstlane(row_ptr[wid]);
    const int end = __builtin_amdgcn_readfirstlane(row_ptr[wid + 1]);
    const float dd = dinv[wid];
    const float* rb = in + (size_t)lane * 2;
    float a0, a1;
    {
        float2 p = *(const float2*)(rb + (size_t)wid * 128);
        a0 = dd * p.x;
        a1 = dd * p.y;
    }
#define GTH(q) (*(const float2*)(rb + (size_t)(q).x * 128))
#define ACC(b, w) a0 += (w) * (b).x; a1 += (w) * (b).y;
    for (; e + 8 <= end; e += 8) {
        int2 q0 = esw[e + 0], q1 = esw[e + 1], q2 = esw[e + 2], q3 = esw[e + 3];
        int2 q4 = esw[e + 4], q5 = esw[e + 5], q6 = esw[e + 6], q7 = esw[e + 7];
        float2 b0 = GTH(q0), b1 = GTH(q1), b2 = GTH(q2), b3 = GTH(q3);
        float2 b4 = GTH(q4), b5 = GTH(q5), b6 = GTH(q6), b7 = GTH(q7);
        ACC(b0, __int_as_float(q0.y)) ACC(b1, __int_as_float(q1.y))
        ACC(b2, __int_as_float(q2.y)) ACC(b3, __int_as_float(q3.y))
        ACC(b4, __int_as_float(q4.y)) ACC(b5, __int_as_float(q5.y))
        ACC(b6, __int_as_float(q6.y)) ACC(b7, __int_as_float(q7.y))
    }
    if (e + 4 <= end) {
        int2 q0 = esw[e + 0], q1 = esw[e + 1], q2 = esw[e + 2], q3 = esw[e + 3];
        float2 b0 = GTH(q0), b1 = GTH(q1), b2 = GTH(q2), b3 = GTH(q3);
        ACC(b0, __int_as_float(q0.y)) ACC(b1, __int_as_float(q1.y))
        ACC(b2, __int_as_float(q2.y)) ACC(b3, __int_as_float(q3.y))
        e += 4;
    }
    if (e < end) {
        const int em = end - 1;
        int e1 = (e + 1 < end) ? e + 1 : em;
        int e2 = (e + 2 < end) ? e + 2 : em;
        int2 q0 = esw[e], q1 = esw[e1], q2 = esw[e2], q3 = esw[em];
        float w0 = __int_as_float(q0.y);
        float w1 = (e + 1 < end) ? __int_as_float(q1.y) : 0.f;
        float w2 = (e + 2 < end) ? __int_as_float(q2.y) : 0.f;
        float w3 = (e + 3 < end) ? __int_as_float(q3.y) : 0.f;
        float2 b0 = GTH(q0), b1 = GTH(q1), b2 = GTH(q2), b3 = GTH(q3);
        ACC(b0, w0) ACC(b1, w1) ACC(b2, w2) ACC(b3, w3)
    }
#undef GTH
#undef ACC
    size_t o = (size_t)wid * 128 + lane * 2;
    float s0 = dd * a0, s1 = dd * a1;
    _Float16 h0 = (_Float16)s0, h1 = (_Float16)s1;
    *(v2h*)&outH[o] = (v2h){h0, h1};
    *(v2h*)&outL[o] = (v2h){(_Float16)(s0 - (float)h0), (_Float16)(s1 - (float)h1)};
}

// ---------------- GEMM block body (device) ----------------
__device__ __forceinline__ void gl_lds16(const _Float16* g, _Float16* l) {
    __builtin_amdgcn_global_load_lds(
        (const __attribute__((address_space(1))) uint32_t*)g,
        (__attribute__((address_space(3))) uint32_t*)l, 16, 0, 0);
}

// BM=64 x BN=256 x BK=32, 4 waves, 32x32x16 f16x3 (R8-verified). lds = 20480 f16.
template <int FI, int OUTMODE>
__device__ __forceinline__ void gemm_wide_block(
    int m0, const _Float16* __restrict__ Ah, const _Float16* __restrict__ Al,
    const _Float16* __restrict__ Wth, const _Float16* __restrict__ Wtl,
    const float* __restrict__ bias,
    uint32_t* __restrict__ Opk, _Float16* __restrict__ Oh, _Float16* __restrict__ Ol,
    int n, _Float16* lds) {
    constexpr int BK = 32;
    constexpr int NSTEP = FI / BK;
    const int t = threadIdx.x;
    const int w = t >> 6;
    const int lane = t & 63;

    const int arow = w * 16 + (lane & 15);
    const int akc = (lane >> 4) * 8;
    const _Float16* sAh = Ah + (size_t)(m0 + arow) * FI + akc;
    const _Float16* sAl = Al + (size_t)(m0 + arow) * FI + akc;
    _Float16* dAh = &lds[w * 512];
    _Float16* dAl = &lds[2048 + w * 512];
    size_t boff[4];
    #pragma unroll
    for (int q = 0; q < 4; ++q)
        boff[q] = (size_t)((w * 4 + q) * 16 + (lane & 15)) * FI + akc;

    v16f acc[2][2];
    #pragma unroll
    for (int i = 0; i < 2; ++i)
        #pragma unroll
        for (int j = 0; j < 2; ++j) acc[i][j] = (v16f)(0.f);

    const int rsel = (lane >> 4) & 1;
    const int kq = lane >> 5;
    const int l8 = (lane & 15) * 8;

    for (int s = 0; s < NSTEP; ++s) {
        const int ko = s * BK;
        gl_lds16(sAh + ko, dAh);
        gl_lds16(sAl + ko, dAl);
        #pragma unroll
        for (int q = 0; q < 4; ++q) {
            gl_lds16(Wth + boff[q] + ko, &lds[4096 + (w * 4 + q) * 512]);
            gl_lds16(Wtl + boff[q] + ko, &lds[12288 + (w * 4 + q) * 512]);
        }
        __syncthreads();
        v8h ah[2][2], al[2][2], bh[2][2], bl[2][2];
        #pragma unroll
        for (int i = 0; i < 2; ++i)
            #pragma unroll
            for (int ks = 0; ks < 2; ++ks) {
                const int aoff = (i * 2 + rsel) * 512 + (ks * 2 + kq) * 128 + l8;
                ah[i][ks] = *(const v8h*)&lds[aoff];
                al[i][ks] = *(const v8h*)&lds[2048 + aoff];
            }
        #pragma unroll
        for (int j = 0; j < 2; ++j)
            #pragma unroll
            for (int ks = 0; ks < 2; ++ks) {
                const int bo = 4096 + (w * 4 + j * 2 + rsel) * 512 + (ks * 2 + kq) * 128 + l8;
                bh[j][ks] = *(const v8h*)&lds[bo];
                bl[j][ks] = *(const v8h*)&lds[bo + 8192];
            }
        #pragma unroll
        for (int i = 0; i < 2; ++i)
            #pragma unroll
            for (int j = 0; j < 2; ++j)
                #pragma unroll
                for (int ks = 0; ks < 2; ++ks) {
                    acc[i][j] = __builtin_amdgcn_mfma_f32_32x32x16_f16(ah[i][ks], bh[j][ks], acc[i][j], 0, 0, 0);
                    acc[i][j] = __builtin_amdgcn_mfma_f32_32x32x16_f16(ah[i][ks], bl[j][ks], acc[i][j], 0, 0, 0);
                    acc[i][j] = __builtin_amdgcn_mfma_f32_32x32x16_f16(al[i][ks], bh[j][ks], acc[i][j], 0, 0, 0);
                }
        __syncthreads();
    }

    const int col = lane & 31;
    const int rb4 = (lane >> 5) * 4;
    #pragma unroll
    for (int j = 0; j < 2; ++j) {
        const int gcol = w * 64 + j * 32 + col;
        const float bv = bias[gcol];
        #pragma unroll
        for (int i = 0; i < 2; ++i) {
            #pragma unroll
            for (int reg = 0; reg < 16; ++reg) {
                const int row = (reg & 3) + 8 * (reg >> 2) + rb4;
                const int grow = m0 + i * 32 + row;
                if (grow < n) {
                    float v = fmaxf(acc[i][j][reg] + bv, 0.f);
                    _Float16 h = (_Float16)v;
                    _Float16 l = (_Float16)(v - (float)h);
                    if (OUTMODE == 0) {
                        uint32_t u = (uint32_t)__builtin_bit_cast(uint16_t, h) |
                                     ((uint32_t)__builtin_bit_cast(uint16_t, l) << 16);
                        Opk[(size_t)grow * 256 + gcol] = u;
                    } else {
                        Oh[(size_t)grow * 256 + gcol] = h;
                        Ol[(size_t)grow * 256 + gcol] = l;
                    }
                }
            }
        }
    }
}

// ---------------- kernels ----------------
// agg ranges: rows [r0, r1), one wave per row.
__global__ __launch_bounds__(256) void agg_packed_rng(
    const _Float16* __restrict__ inP, const int* __restrict__ row_ptr,
    const int2* __restrict__ esw, const float* __restrict__ dinv,
    _Float16* __restrict__ outH, _Float16* __restrict__ outL, int r0, int r1) {
    int wid = r0 + ((blockIdx.x * blockDim.x + threadIdx.x) >> 6);
    if (wid >= r1) return;
    agg_packed_row(wid, threadIdx.x & 63, inP, row_ptr, esw, dinv, outH, outL);
}

__global__ __launch_bounds__(256) void agg_f128_rng(
    const float* __restrict__ in, const int* __restrict__ row_ptr,
    const int2* __restrict__ esw, const float* __restrict__ dinv,
    _Float16* __restrict__ outH, _Float16* __restrict__ outL, int r0, int r1) {
    int wid = r0 + ((blockIdx.x * blockDim.x + threadIdx.x) >> 6);
    if (wid >= r1) return;
    agg_f128_row(wid, threadIdx.x & 63, in, row_ptr, esw, dinv, outH, outL);
}

// standalone gemm with row offset
template <int FI, int OUTMODE>
__global__ __launch_bounds__(256) void gemm_wide_k(
    int mbase, const _Float16* __restrict__ Ah, const _Float16* __restrict__ Al,
    const _Float16* __restrict__ Wth, const _Float16* __restrict__ Wtl,
    const float* __restrict__ bias,
    uint32_t* __restrict__ Opk, _Float16* __restrict__ Oh, _Float16* __restrict__ Ol, int n) {
    __shared__ _Float16 lds[20480];
    gemm_wide_block<FI, OUTMODE>(mbase + blockIdx.x * 64, Ah, Al, Wth, Wtl, bias,
                                 Opk, Oh, Ol, n, lds);
}

// MIX: blocks [0,GB) = gemm on rows [0, GB*64); blocks [GB,..) = agg rows [H, n).
// AGGMODE 0: f32-128 agg (L1).  AGGMODE 1: packed agg.
template <int FI, int OUTMODE, int AGGMODE>
__global__ __launch_bounds__(256, 4) void mix_k(
    const _Float16* __restrict__ Ah, const _Float16* __restrict__ Al,
    const _Float16* __restrict__ Wth, const _Float16* __restrict__ Wtl,
    const float* __restrict__ bias,
    uint32_t* __restrict__ Opk, _Float16* __restrict__ OhG, _Float16* __restrict__ OlG,
    const void* __restrict__ aggIn, const int* __restrict__ row_ptr,
    const int2* __restrict__ esw, const float* __restrict__ dinv,
    _Float16* __restrict__ aggOutH, _Float16* __restrict__ aggOutL,
    int GB, int H, int n) {
    __shared__ _Float16 lds[20480];
    if ((int)blockIdx.x < GB) {
        gemm_wide_block<FI, OUTMODE>(blockIdx.x * 64, Ah, Al, Wth, Wtl, bias,
                                     Opk, OhG, OlG, n, lds);
    } else {
        int wid = H + (((blockIdx.x - GB) * blockDim.x + threadIdx.x) >> 6);
        if (wid >= n) return;
        const int lane = threadIdx.x & 63;
        if (AGGMODE == 1)
            agg_packed_row(wid, lane, (const _Float16*)aggIn, row_ptr, esw, dinv, aggOutH, aggOutL);
        else
            agg_f128_row(wid, lane, (const float*)aggIn, row_ptr, esw, dinv, aggOutH, aggOutL);
    }
}

// Narrow GEMM for L5 (R8 single-buffer, verified).
__global__ __launch_bounds__(256) void gemm_narrow(
    const _Float16* __restrict__ Ah, const _Float16* __restrict__ Al,
    const _Float16* __restrict__ Wth, const _Float16* __restrict__ Wtl,
    float* __restrict__ Of, int n) {
    constexpr int FI = 256, FO = 64;
    __shared__ _Float16 lds[12288];
    const int m0 = blockIdx.x * 128;
    const int t = threadIdx.x;
    const int w = t >> 6;
    const int lane = t & 63;

    const int G0 = w * 128 + lane;
    const int G1 = G0 + 64;
    const int arow0 = (G0 >> 6) * 16 + (G0 & 15), akc0 = ((G0 >> 4) & 3) * 8;
    const int arow1 = (G1 >> 6) * 16 + (G1 & 15), akc1 = ((G1 >> 4) & 3) * 8;
    const _Float16* sAh0 = Ah + (size_t)(m0 + arow0) * FI + akc0;
    const _Float16* sAh1 = Ah + (size_t)(m0 + arow1) * FI + akc1;
    const _Float16* sAl0 = Al + (size_t)(m0 + arow0) * FI + akc0;
    const _Float16* sAl1 = Al + (size_t)(m0 + arow1) * FI + akc1;
    const int bcol = w * 16 + (lane & 15), bkc = (lane >> 4) * 8;
    const _Float16* sBh = Wth + (size_t)bcol * FI + bkc;
    const _Float16* sBl = Wtl + (size_t)bcol * FI + bkc;

    _Float16* dAh0 = &lds[w * 1024];
    _Float16* dAh1 = &lds[w * 1024 + 512];
    _Float16* dAl0 = &lds[4096 + w * 1024];
    _Float16* dAl1 = &lds[4096 + w * 1024 + 512];
    _Float16* dBh = &lds[8192 + w * 512];
    _Float16* dBl = &lds[10240 + w * 512];

    const int wm = w >> 1, wn = w & 1;
    v4f acc[4][2];
    #pragma unroll
    for (int i = 0; i < 4; ++i)
        #pragma unroll
        for (int j = 0; j < 2; ++j) acc[i][j] = (v4f){0.f, 0.f, 0.f, 0.f};

    for (int s = 0; s < 8; ++s) {
        const int ko = s * 32;
        gl_lds16(sAh0 + ko, dAh0);
        gl_lds16(sAh1 + ko, dAh1);
        gl_lds16(sAl0 + ko, dAl0);
        gl_lds16(sAl1 + ko, dAl1);
        gl_lds16(sBh + ko, dBh);
        gl_lds16(sBl + ko, dBl);
        __syncthreads();
        v8h ah[4], al[4], bh[2], bl[2];
        #pragma unroll
        for (int i = 0; i < 4; ++i) {
            ah[i] = *(const v8h*)&lds[(wm * 4 + i) * 512 + lane * 8];
            al[i] = *(const v8h*)&lds[4096 + (wm * 4 + i) * 512 + lane * 8];
        }
        #pragma unroll
        for (int j = 0; j < 2; ++j) {
            bh[j] = *(const v8h*)&lds[8192 + (wn * 2 + j) * 512 + lane * 8];
            bl[j] = *(const v8h*)&lds[10240 + (wn * 2 + j) * 512 + lane * 8];
        }
        #pragma unroll
        for (int i = 0; i < 4; ++i)
            #pragma unroll
            for (int j = 0; j < 2; ++j) {
                acc[i][j] = __builtin_amdgcn_mfma_f32_16x16x32_f16(ah[i], bh[j], acc[i][j], 0, 0, 0);
                acc[i][j] = __builtin_amdgcn_mfma_f32_16x16x32_f16(ah[i], bl[j], acc[i][j], 0, 0, 0);
                acc[i][j] = __builtin_amdgcn_mfma_f32_16x16x32_f16(al[i], bh[j], acc[i][j], 0, 0, 0);
            }
        __syncthreads();
    }

    const int rl = (lane >> 4) * 4;
    const int cl = lane & 15;
    #pragma unroll
    for (int j = 0; j < 2; ++j) {
        const int gcol = wn * 32 + j * 16 + cl;
        #pragma unroll
        for (int i = 0; i < 4; ++i) {
            const int grow = m0 + wm * 64 + i * 16 + rl;
            #pragma unroll
            for (int r = 0; r < 4; ++r)
                if (grow + r < n) Of[(size_t)(grow + r) * FO + gcol] = acc[i][j][r];
        }
    }
}

// L5 aggregation: f32 64 feats + bias (unchanged).
__global__ __launch_bounds__(256) void agg_f32_64(
    const float* __restrict__ in, const int* __restrict__ row_ptr,
    const int2* __restrict__ esw, const float* __restrict__ dinv,
    const float* __restrict__ bias, float* __restrict__ outF, int n) {
    int wid = (blockIdx.x * blockDim.x + threadIdx.x) >> 6;
    if (wid >= n) return;
    const int lane = threadIdx.x & 63;
    int e = __builtin_amdgcn_readfirstlane(row_ptr[wid]);
    const int end = __builtin_amdgcn_readfirstlane(row_ptr[wid + 1]);
    const float dd = dinv[wid];
    const float* rb = in + lane;
    float a0 = dd * rb[(size_t)wid * 64];
#define GTH(q) (rb[(size_t)(q).x * 64])
    for (; e + 8 <= end; e += 8) {
        int2 q0 = esw[e + 0], q1 = esw[e + 1], q2 = esw[e + 2], q3 = esw[e + 3];
        int2 q4 = esw[e + 4], q5 = esw[e + 5], q6 = esw[e + 6], q7 = esw[e + 7];
        float b0 = GTH(q0), b1 = GTH(q1), b2 = GTH(q2), b3 = GTH(q3);
        float b4 = GTH(q4), b5 = GTH(q5), b6 = GTH(q6), b7 = GTH(q7);
        a0 += __int_as_float(q0.y) * b0 + __int_as_float(q1.y) * b1;
        a0 += __int_as_float(q2.y) * b2 + __int_as_float(q3.y) * b3;
        a0 += __int_as_float(q4.y) * b4 + __int_as_float(q5.y) * b5;
        a0 += __int_as_float(q6.y) * b6 + __int_as_float(q7.y) * b7;
    }
    if (e + 4 <= end) {
        int2 q0 = esw[e + 0], q1 = esw[e + 1], q2 = esw[e + 2], q3 = esw[e + 3];
        float b0 = GTH(q0), b1 = GTH(q1), b2 = GTH(q2), b3 = GTH(q3);
        a0 += __int_as_float(q0.y) * b0 + __int_as_float(q1.y) * b1;
        a0 += __int_as_float(q2.y) * b2 + __int_as_float(q3.y) * b3;
        e += 4;
    }
    if (e < end) {
        const int em = end - 1;
        int e1 = (e + 1 < end) ? e + 1 : em;
        int e2 = (e + 2 < end) ? e + 2 : em;
        int2 q0 = esw[e], q1 = esw[e1], q2 = esw[e2], q3 = esw[em];
        float w0 = __int_as_float(q0.y);
        float w1 = (e + 1 < end) ? __int_as_float(q1.y) : 0.f;
        float w2 = (e + 2 < end) ? __int_as_float(q2.y) : 0.f;
        float w3 = (e + 3 < end) ? __int_as_float(q3.y) : 0.f;
        float b0 = GTH(q0), b1 = GTH(q1), b2 = GTH(q2), b3 = GTH(q3);
        a0 += w0 * b0 + w1 * b1 + w2 * b2 + w3 * b3;
    }
#undef GTH
    outF[(size_t)wid * 64 + lane] = dd * a0 + bias[lane];
}

// ---------------- launcher ----------------
extern "C" void kernel_launch(void* const* d_in, const int* in_sizes, int n_in,
                              void* d_out, int out_size, void* d_ws, size_t ws_size,
                              hipStream_t stream) {
    const float* x = (const float*)d_in[0];
    const int* ei = (const int*)d_in[1];
    const int E = in_sizes[1] / 2;
    const int n = in_sizes[0] / 128;
    const int* esrc = ei;
    const int* edst = ei + E;
    const float* b[5] = {(const float*)d_in[3], (const float*)d_in[5], (const float*)d_in[7],
                         (const float*)d_in[9], (const float*)d_in[11]};
    float* out = (float*)d_out;
    const int NPAD = ((n + 127) / 128) * 128;
    const int H = (NPAD / 2) & ~63;  // row split point (64-aligned, <= n)

    char* ws = (char*)d_ws;
    auto carve = [&](size_t bytes) {
        char* p = ws;
        ws += (bytes + 255) & ~(size_t)255;
        return p;
    };
    int* counts = (int*)carve((size_t)n * 4);
    int* row_ptr = (int*)carve((size_t)(n + 1) * 4);
    int* fill = (int*)carve((size_t)n * 4);
    float* dinv = (float*)carve((size_t)n * 4);
    int* partial = (int*)carve(1024);
    int2* esw = (int2*)carve((size_t)E * 8);
    const int FIs[5] = {128, 256, 256, 256, 256};
    const int FOs[5] = {256, 256, 256, 256, 64};
    _Float16 *Wh[5], *Wl[5];
    for (int l = 0; l < 5; ++l) {
        Wh[l] = (_Float16*)carve((size_t)FIs[l] * FOs[l] * 2);
        Wl[l] = (_Float16*)carve((size_t)FIs[l] * FOs[l] * 2);
    }
    _Float16* Ah = (_Float16*)carve((size_t)NPAD * 256 * 2);
    _Float16* Al = (_Float16*)carve((size_t)NPAD * 256 * 2);
    uint32_t* P0 = (uint32_t*)carve((size_t)NPAD * 256 * 4);
    uint32_t* P1 = (uint32_t*)carve((size_t)NPAD * 256 * 4);
    _Float16* Bh2 = (_Float16*)P1;                    // L4 planes out (P1 dead by L4)
    _Float16* Bl2 = (_Float16*)P1 + (size_t)NPAD * 256;
    float* scratch = (float*)Ah;                      // L5 gemm f32 out

    hipMemsetAsync(counts, 0, (size_t)n * 4, stream);
    count_edges<<<(E + 255) / 256, 256, 0, stream>>>(edst, E, counts);
    const int nsb = (n + 255) / 256;
    block_sums<<<nsb, 256, 0, stream>>>(counts, n, partial);
    scan_partials<<<1, 256, 0, stream>>>(partial, nsb, row_ptr, n);
    scan_final<<<nsb, 256, 0, stream>>>(counts, n, partial, row_ptr, dinv, fill);
    build_csr<<<(E + 255) / 256, 256, 0, stream>>>(esrc, edst, E, row_ptr, fill, esw, dinv);

    SplitArgs sa;
    int off = 0;
    for (int l = 0; l < 5; ++l) {
        sa.W[l] = (const float*)d_in[2 + 2 * l];
        sa.Wh[l] = Wh[l];
        sa.Wl[l] = Wl[l];
        sa.lgFI[l] = (FIs[l] == 128) ? 7 : 8;
        sa.FO[l] = FOs[l];
        sa.off[l] = off;
        off += FIs[l] * FOs[l];
    }
    sa.off[5] = off;
    split_all<<<(off + 255) / 256, 256, 0, stream>>>(sa);

    const int GB1 = H / 64;                 // gemm blocks for half-1
    const int GB2 = (NPAD - H) / 64;        // gemm blocks for half-2
    const int AB1 = (H + 3) / 4;            // agg blocks rows [0,H)
    const int AB2 = (n - H + 3) / 4;        // agg blocks rows [H,n)

    // ---- L1 ----
    agg_f128_rng<<<AB1, 256, 0, stream>>>(x, row_ptr, esw, dinv, Ah, Al, 0, H);
    mix_k<128, 0, 0><<<GB1 + AB2, 256, 0, stream>>>(Ah, Al, Wh[0], Wl[0], b[0],
                                                    P0, nullptr, nullptr,
                                                    x, row_ptr, esw, dinv, Ah, Al, GB1, H, n);
    gemm_wide_k<128, 0><<<GB2, 256, 0, stream>>>(H, Ah, Al, Wh[0], Wl[0], b[0],
                                                 P0, nullptr, nullptr, n);
    // ---- L2 (P0 -> P1), L3 (P1 -> P0) ----
    uint32_t* Pin = P0;
    uint32_t* Pout = P1;
    for (int l = 1; l <= 2; ++l) {
        agg_packed_rng<<<AB1, 256, 0, stream>>>((const _Float16*)Pin, row_ptr, esw, dinv,
                                                Ah, Al, 0, H);
        mix_k<256, 0, 1><<<GB1 + AB2, 256, 0, stream>>>(Ah, Al, Wh[l], Wl[l], b[l],
                                                        Pout, nullptr, nullptr,
                                                        Pin, row_ptr, esw, dinv, Ah, Al, GB1, H, n);
        gemm_wide_k<256, 0><<<GB2, 256, 0, stream>>>(H, Ah, Al, Wh[l], Wl[l], b[l],
                                                     Pout, nullptr, nullptr, n);
        uint32_t* tmp = Pin; Pin = Pout; Pout = tmp;
    }
    // ---- L4 (Pin = P0 -> planes in P1 region) ----
    agg_packed_rng<<<AB1, 256, 0, stream>>>((const _Float16*)Pin, row_ptr, esw, dinv, Ah, Al, 0, H);
    mix_k<256, 1, 1><<<GB1 + AB2, 256, 0, stream>>>(Ah, Al, Wh[3], Wl[3], b[3],
                                                    nullptr, Bh2, Bl2,
                                                    Pin, row_ptr, esw, dinv, Ah, Al, GB1, H, n);
    gemm_wide_k<256, 1><<<GB2, 256, 0, stream>>>(H, Ah, Al, Wh[3], Wl[3], b[3],
                                                 nullptr, Bh2, Bl2, n);
    // ---- L5 ----
    gemm_narrow<<<NPAD / 128, 256, 0, stream>>>(Bh2, Bl2, Wh[4], Wl[4], scratch, n);
    agg_f32_64<<<(n + 3) / 4, 256, 0, stream>>>(scratch, row_ptr, esw, dinv, b[4], out, n);
}